// Round 17
// baseline (119.122 us; speedup 1.0000x reference)
//
#include <hip/hip_runtime.h>

typedef float  f32x4  __attribute__((ext_vector_type(4)));
typedef short  bf16x8 __attribute__((ext_vector_type(8)));
typedef unsigned int u32;
typedef u32 u32x4 __attribute__((ext_vector_type(4)));

#define HID  20
#define NLAY 7
#define NC   11      // 0=val 1=gx 2=gy 3=gt 4=hxx 5=hxy 6=hyy 7=hxt 8=hyt 9=Lx 10=Ly
#define NLO  3       // comps with hi+lo X (val,gx,gy: nonlinearly amplified / direct O(1) outputs)
#define NWL  9       // comps 0..NWL-1 include the W-lo MFMA term (9,10 are lam2-damped)
#define PTS  16      // points per wave

__device__ __forceinline__ float tanh_derivs(float a, float& d1, float& d2, float& d3) {
    const float e = __expf(2.0f * a);
    const float s = 1.0f - __fdividef(2.0f, e + 1.0f);
    d1 = 1.0f - s * s;
    d2 = -2.0f * s * d1;
    d3 = -2.0f * (d1 * d1 + s * d2);
    return s;
}

// jet chain rule through tanh: a[] = pre-activation jet, nv[] = post-activation jet
__device__ __forceinline__ void jet_activate(const float* a, float* nv) {
    float d1, d2, d3;
    const float s = tanh_derivs(a[0], d1, d2, d3);
    const float gx = a[1], gy = a[2], gt = a[3];
    const float hxx = a[4], hxy = a[5], hyy = a[6];
    const float hxt = a[7], hyt = a[8];
    const float g2 = gx * gx + gy * gy;
    nv[0] = s;
    nv[1] = d1 * gx;  nv[2] = d1 * gy;  nv[3] = d1 * gt;
    nv[4] = fmaf(d2, gx * gx, d1 * hxx);
    nv[5] = fmaf(d2, gx * gy, d1 * hxy);
    nv[6] = fmaf(d2, gy * gy, d1 * hyy);
    nv[7] = fmaf(d2, gx * gt, d1 * hxt);
    nv[8] = fmaf(d2, gy * gt, d1 * hyt);
    nv[9]  = d3 * gx * g2 + d2 * (3.f * gx * hxx + 2.f * gy * hxy + gx * hyy) + d1 * a[9];
    nv[10] = d3 * gy * g2 + d2 * (3.f * gy * hyy + 2.f * gx * hxy + gy * hxx) + d1 * a[10];
}

// packed bf16 convert: dst.lo16 = bf16(a), dst.hi16 = bf16(b)  (RNE)
__device__ __forceinline__ u32 cvt_pk_bf16(float a, float b) {
    u32 r;
    asm("v_cvt_pk_bf16_f32 %0, %1, %2" : "=v"(r) : "v"(a), "v"(b));
    return r;
}

// hi word + exact residual lo word
__device__ __forceinline__ void pack_pair(float v0, float v1, u32& wh, u32& wl) {
    wh = cvt_pk_bf16(v0, v1);
    const float h0 = __uint_as_float(wh << 16);
    const float h1 = __uint_as_float(wh & 0xFFFF0000u);
    wl = cvt_pk_bf16(v0 - h0, v1 - h1);
}

__device__ __forceinline__ void input_neuron(int j, float xv, float yv, float tv,
                                             const float* __restrict__ W_in,
                                             const float* __restrict__ b_in, float* nv) {
    const float w0 = W_in[j], w1 = W_in[HID + j], w2 = W_in[2 * HID + j];
    const float a0 = fmaf(xv, w0, fmaf(yv, w1, fmaf(tv, w2, b_in[j])));
    float d1, d2, d3;
    const float s = tanh_derivs(a0, d1, d2, d3);
    const float g2w = w0 * w0 + w1 * w1;
    nv[0] = s;        nv[1] = d1 * w0;  nv[2] = d1 * w1;  nv[3] = d1 * w2;
    nv[4] = d2 * w0 * w0; nv[5] = d2 * w0 * w1; nv[6] = d2 * w1 * w1;
    nv[7] = d2 * w0 * w2; nv[8] = d2 * w1 * w2;
    nv[9] = d3 * w0 * g2w; nv[10] = d3 * w1 * g2w;
}

// ---- setup: pack W_hid (+bias at k=20) into MFMA A-fragments (hi/lo bf16) in ws ----
// HW-verified (r11/r13/r14): lane l holds m=l&15, e<4: k=4*(l>>4)+e ; e>=4: k=16+4*(l>>4)+(e-4)
__global__ void wfrag_setup(const float* __restrict__ W_hid,
                            const float* __restrict__ b_hid,
                            unsigned* __restrict__ wsu)
{
    const int l = threadIdx.x;
    const int g = l >> 4, m = l & 15;
    for (int layer = 0; layer < NLAY; ++layer) {
        for (int jt = 0; jt < 2; ++jt) {
            const int j = jt * 16 + m;
            unsigned hi[8], lo[8];
            for (int e = 0; e < 8; ++e) {
                const int k = (e < 4) ? (4 * g + e) : (16 + 4 * g + (e - 4));
                float w = 0.0f;
                if (j < HID) {
                    if (k < HID)       w = W_hid[(layer * HID + k) * HID + j];
                    else if (k == HID) w = b_hid[layer * HID + j];
                }
                const unsigned hb = __float_as_uint(w) & 0xFFFF0000u;
                const float lf = w - __uint_as_float(hb);
                hi[e] = hb >> 16;
                lo[e] = __float_as_uint(lf) >> 16;
            }
            unsigned* ph = wsu + (((layer * 2 + jt) * 2 + 0) * 64 + l) * 4;
            unsigned* pl = wsu + (((layer * 2 + jt) * 2 + 1) * 64 + l) * 4;
            for (int r = 0; r < 4; ++r) {
                ph[r] = hi[2 * r] | (hi[2 * r + 1] << 16);
                pl[r] = lo[2 * r] | (lo[2 * r + 1] << 16);
            }
        }
    }
}

__global__ void __launch_bounds__(256)
pinn_mfma_reg(const float* __restrict__ xs, const float* __restrict__ ys, const float* __restrict__ ts,
              const float* __restrict__ W_in, const float* __restrict__ b_in,
              const float* __restrict__ W_out, const float* __restrict__ b_out,
              const float* __restrict__ lam1p, const float* __restrict__ lam2p,
              const unsigned* __restrict__ wsu,
              float* __restrict__ out, int N)
{
    const int l  = threadIdx.x & 63;        // lane within wave
    const int wid = threadIdx.x >> 6;       // wave within block (0..3)
    const int g  = l >> 4, pt = l & 15;
    const int idx0 = blockIdx.x * (4 * PTS) + wid * PTS;
    const int pi = min(idx0 + pt, N - 1);

    // Layer-input B-fragments, register-resident.
    // comps 0..2 (val,gx,gy): hi+lo (exact).  comps 3..10: hi-only bf16 (linear
    // d1-contraction propagation; r16 measured zero absmax impact for 4..10).
    // comps 9,10 additionally skip the W-lo MFMA term (outputs see them via lam2=0.01).
    u32x4 Bh[NC], Bl[NLO];

    // ---- input layer ----
    const float xv = xs[pi], yv = ys[pi], tv = ts[pi];
    #pragma unroll
    for (int pr = 0; pr < 2; ++pr) {
        float nvA[NC], nvB[NC];
        input_neuron(4 * g + 2 * pr,     xv, yv, tv, W_in, b_in, nvA);
        input_neuron(4 * g + 2 * pr + 1, xv, yv, tv, W_in, b_in, nvB);
        #pragma unroll
        for (int c = 0; c < NC; ++c) {
            if (c < NLO) {
                u32 th, tl;
                pack_pair(nvA[c], nvB[c], th, tl);
                Bh[c][pr] = th; Bl[c][pr] = tl;
            } else {
                Bh[c][pr] = cvt_pk_bf16(nvA[c], nvB[c]);
            }
        }
    }
    if (g == 0) {
        #pragma unroll
        for (int pr = 0; pr < 2; ++pr) {
            float nvA[NC], nvB[NC];
            input_neuron(16 + 2 * pr,     xv, yv, tv, W_in, b_in, nvA);
            input_neuron(16 + 2 * pr + 1, xv, yv, tv, W_in, b_in, nvB);
            #pragma unroll
            for (int c = 0; c < NC; ++c) {
                if (c < NLO) {
                    u32 th, tl;
                    pack_pair(nvA[c], nvB[c], th, tl);
                    Bh[c][2 + pr] = th; Bl[c][2 + pr] = tl;
                } else {
                    Bh[c][2 + pr] = cvt_pk_bf16(nvA[c], nvB[c]);
                }
            }
        }
    } else {
        #pragma unroll
        for (int c = 0; c < NC; ++c) { Bh[c][2] = 0u; Bh[c][3] = 0u; }
        #pragma unroll
        for (int c = 0; c < NLO; ++c) { Bl[c][2] = 0u; Bl[c][3] = 0u; }
    }
    // bias row k=20 (g==1, e=4): X=1.0 in comp 0 only
    Bh[0][2] = (g == 1) ? 0x3F80u : Bh[0][2];
    Bl[0][2] = (g == 1) ? 0u      : Bl[0][2];

    // ---- hidden layers 0..NLAY-2: MFMA + activation + repack ----
    const u32x4* wp = (const u32x4*)wsu;
    u32x4 f0 = wp[0 * 64 + l];
    u32x4 f1 = wp[1 * 64 + l];
    u32x4 f2 = wp[2 * 64 + l];
    u32x4 f3 = wp[3 * 64 + l];

    #pragma unroll 1
    for (int layer = 0; layer < NLAY - 1; ++layer) {
        const int nl = layer + 1;
        u32x4 n0 = wp[(nl * 4 + 0) * 64 + l];
        u32x4 n1 = wp[(nl * 4 + 1) * 64 + l];
        u32x4 n2 = wp[(nl * 4 + 2) * 64 + l];
        u32x4 n3 = wp[(nl * 4 + 3) * 64 + l];

        const bf16x8 ah0 = __builtin_bit_cast(bf16x8, f0);
        const bf16x8 al0 = __builtin_bit_cast(bf16x8, f1);
        const bf16x8 ah1 = __builtin_bit_cast(bf16x8, f2);
        const bf16x8 al1 = __builtin_bit_cast(bf16x8, f3);

        f32x4 acc1[NC], acc2[NC];
        #pragma unroll
        for (int c = 0; c < NC; ++c) {
            const bf16x8 bh = __builtin_bit_cast(bf16x8, Bh[c]);
            const f32x4 z = (f32x4){0.f, 0.f, 0.f, 0.f};
            f32x4 a1 = __builtin_amdgcn_mfma_f32_16x16x32_bf16(ah0, bh, z, 0, 0, 0);
            f32x4 a2 = __builtin_amdgcn_mfma_f32_16x16x32_bf16(ah1, bh, z, 0, 0, 0);
            if (c < NLO) {
                const bf16x8 bl = __builtin_bit_cast(bf16x8, Bl[c]);
                a1 = __builtin_amdgcn_mfma_f32_16x16x32_bf16(ah0, bl, a1, 0, 0, 0);
                a2 = __builtin_amdgcn_mfma_f32_16x16x32_bf16(ah1, bl, a2, 0, 0, 0);
            }
            if (c < NWL) {
                a1 = __builtin_amdgcn_mfma_f32_16x16x32_bf16(al0, bh, a1, 0, 0, 0);
                a2 = __builtin_amdgcn_mfma_f32_16x16x32_bf16(al1, bh, a2, 0, 0, 0);
            }
            acc1[c] = a1;
            acc2[c] = a2;
        }

        // activation + repack (uniform across lanes: g>0 tile2 accs are exactly 0)
        #pragma unroll
        for (int pr = 0; pr < 2; ++pr) {
            float aA[NC], aB[NC], nvA[NC], nvB[NC];
            #pragma unroll
            for (int c = 0; c < NC; ++c) { aA[c] = acc1[c][2 * pr]; aB[c] = acc1[c][2 * pr + 1]; }
            jet_activate(aA, nvA);
            jet_activate(aB, nvB);
            #pragma unroll
            for (int c = 0; c < NC; ++c) {
                if (c < NLO) {
                    u32 th, tl;
                    pack_pair(nvA[c], nvB[c], th, tl);
                    Bh[c][pr] = th; Bl[c][pr] = tl;
                } else {
                    Bh[c][pr] = cvt_pk_bf16(nvA[c], nvB[c]);
                }
            }
        }
        #pragma unroll
        for (int pr = 0; pr < 2; ++pr) {
            float aA[NC], aB[NC], nvA[NC], nvB[NC];
            #pragma unroll
            for (int c = 0; c < NC; ++c) { aA[c] = acc2[c][2 * pr]; aB[c] = acc2[c][2 * pr + 1]; }
            jet_activate(aA, nvA);
            jet_activate(aB, nvB);
            #pragma unroll
            for (int c = 0; c < NC; ++c) {
                if (c < NLO) {
                    u32 th, tl;
                    pack_pair(nvA[c], nvB[c], th, tl);
                    Bh[c][2 + pr] = th; Bl[c][2 + pr] = tl;
                } else {
                    Bh[c][2 + pr] = cvt_pk_bf16(nvA[c], nvB[c]);
                }
            }
        }
        Bh[0][2] = (g == 1) ? 0x3F80u : Bh[0][2];
        Bl[0][2] = (g == 1) ? 0u      : Bl[0][2];

        f0 = n0; f1 = n1; f2 = n2; f3 = n3;
    }

    // ---- last hidden layer: MFMA + activation fused directly into output reduction ----
    float su = 0, sv = 0, sp = 0, spx = 0, spy = 0, svx = 0;
    float sux = 0, suy = 0, svt = 0, sut = 0, slx = 0, sly = 0;
    {
        const bf16x8 ah0 = __builtin_bit_cast(bf16x8, f0);
        const bf16x8 al0 = __builtin_bit_cast(bf16x8, f1);
        const bf16x8 ah1 = __builtin_bit_cast(bf16x8, f2);
        const bf16x8 al1 = __builtin_bit_cast(bf16x8, f3);

        f32x4 acc1[NC], acc2[NC];
        #pragma unroll
        for (int c = 0; c < NC; ++c) {
            const bf16x8 bh = __builtin_bit_cast(bf16x8, Bh[c]);
            const f32x4 z = (f32x4){0.f, 0.f, 0.f, 0.f};
            f32x4 a1 = __builtin_amdgcn_mfma_f32_16x16x32_bf16(ah0, bh, z, 0, 0, 0);
            f32x4 a2 = __builtin_amdgcn_mfma_f32_16x16x32_bf16(ah1, bh, z, 0, 0, 0);
            if (c < NLO) {
                const bf16x8 bl = __builtin_bit_cast(bf16x8, Bl[c]);
                a1 = __builtin_amdgcn_mfma_f32_16x16x32_bf16(ah0, bl, a1, 0, 0, 0);
                a2 = __builtin_amdgcn_mfma_f32_16x16x32_bf16(ah1, bl, a2, 0, 0, 0);
            }
            if (c < NWL) {
                a1 = __builtin_amdgcn_mfma_f32_16x16x32_bf16(al0, bh, a1, 0, 0, 0);
                a2 = __builtin_amdgcn_mfma_f32_16x16x32_bf16(al1, bh, a2, 0, 0, 0);
            }
            acc1[c] = a1;
            acc2[c] = a2;
        }

        // tile1 slots: j = 4g+s, all real
        #pragma unroll
        for (int s = 0; s < 4; ++s) {
            float a[NC], nv[NC];
            #pragma unroll
            for (int c = 0; c < NC; ++c) a[c] = acc1[c][s];
            jet_activate(a, nv);
            const int j = 4 * g + s;
            const float w0 = W_out[2 * j], w1 = W_out[2 * j + 1];
            sp  = fmaf(w1, nv[0], sp);
            sv  = fmaf(w0, nv[1], sv);    spx = fmaf(w1, nv[1], spx);
            su  = fmaf(w0, nv[2], su);    spy = fmaf(w1, nv[2], spy);
            svx = fmaf(w0, nv[4], svx);
            sux = fmaf(w0, nv[5], sux);
            suy = fmaf(w0, nv[6], suy);
            svt = fmaf(w0, nv[7], svt);
            sut = fmaf(w0, nv[8], sut);
            slx = fmaf(w0, nv[9], slx);
            sly = fmaf(w0, nv[10], sly);
        }
        // tile2 slots: j2 = 16+4g+s, real only for j2 < 20 (g==0); others zero accs + masked w
        #pragma unroll
        for (int s = 0; s < 4; ++s) {
            float a[NC], nv[NC];
            #pragma unroll
            for (int c = 0; c < NC; ++c) a[c] = acc2[c][s];
            jet_activate(a, nv);
            const int j2 = 16 + 4 * g + s;
            const int jc = (j2 < HID) ? j2 : 0;
            const float valid = (j2 < HID) ? 1.0f : 0.0f;
            const float w0 = W_out[2 * jc] * valid, w1 = W_out[2 * jc + 1] * valid;
            sp  = fmaf(w1, nv[0], sp);
            sv  = fmaf(w0, nv[1], sv);    spx = fmaf(w1, nv[1], spx);
            su  = fmaf(w0, nv[2], su);    spy = fmaf(w1, nv[2], spy);
            svx = fmaf(w0, nv[4], svx);
            sux = fmaf(w0, nv[5], sux);
            suy = fmaf(w0, nv[6], suy);
            svt = fmaf(w0, nv[7], svt);
            sut = fmaf(w0, nv[8], sut);
            slx = fmaf(w0, nv[9], slx);
            sly = fmaf(w0, nv[10], sly);
        }
    }

    // reduce over the 4 lane-groups (lanes l, l^16, l^32, l^48 share pt)
    #define RED_(x) x += __shfl_xor(x, 16); x += __shfl_xor(x, 32)
    RED_(su); RED_(sv); RED_(sp); RED_(spx); RED_(spy); RED_(svx);
    RED_(sux); RED_(suy); RED_(svt); RED_(sut); RED_(slx); RED_(sly);
    #undef RED_

    if (g == 0 && idx0 + pt < N) {
        const float l1 = lam1p[0], l2 = lam2p[0];
        const float u = su, v = -sv, p = sp + b_out[1];
        const float fu = sut + l1 * (u * sux + v * suy) + spx - l2 * sly;
        const float fv = -svt + l1 * (u * (-svx) + v * (-sux)) + spy + l2 * slx;
        out[idx0 + pt]         = u;
        out[N + idx0 + pt]     = v;
        out[2 * N + idx0 + pt] = p;
        out[3 * N + idx0 + pt] = fu;
        out[4 * N + idx0 + pt] = fv;
    }
}

extern "C" void kernel_launch(void* const* d_in, const int* in_sizes, int n_in,
                              void* d_out, int out_size, void* d_ws, size_t ws_size,
                              hipStream_t stream) {
    const float* xs    = (const float*)d_in[0];
    const float* ys    = (const float*)d_in[1];
    const float* ts    = (const float*)d_in[2];
    const float* W_in  = (const float*)d_in[3];
    const float* b_in  = (const float*)d_in[4];
    const float* W_hid = (const float*)d_in[5];
    const float* b_hid = (const float*)d_in[6];
    const float* W_out = (const float*)d_in[7];
    const float* b_out = (const float*)d_in[8];
    const float* lam1  = (const float*)d_in[9];
    const float* lam2  = (const float*)d_in[10];
    float* out = (float*)d_out;

    const int N = in_sizes[0];
    wfrag_setup<<<1, 64, 0, stream>>>(W_hid, b_hid, (unsigned*)d_ws);
    const int grid = (N + 4 * PTS - 1) / (4 * PTS);
    pinn_mfma_reg<<<grid, 256, 0, stream>>>(xs, ys, ts, W_in, b_in, W_out, b_out,
                                            lam1, lam2, (const unsigned*)d_ws, out, N);
}

// Round 18
// 111.048 us; speedup vs baseline: 1.0727x; 1.0727x over previous
//
#include <hip/hip_runtime.h>

typedef float  f32x4  __attribute__((ext_vector_type(4)));
typedef short  bf16x8 __attribute__((ext_vector_type(8)));
typedef unsigned int u32;
typedef u32 u32x4 __attribute__((ext_vector_type(4)));

#define HID  20
#define NLAY 7
#define NC   11      // 0=val 1=gx 2=gy 3=gt 4=hxx 5=hxy 6=hyy 7=hxt 8=hyt 9=Lx 10=Ly
#define NLO  4       // comps with hi+lo X representation (nonlinearly amplified ones)
#define PTS  16      // points per wave

__device__ __forceinline__ float tanh_derivs(float a, float& d1, float& d2, float& d3) {
    const float e = __expf(2.0f * a);
    const float s = 1.0f - __fdividef(2.0f, e + 1.0f);
    d1 = 1.0f - s * s;
    d2 = -2.0f * s * d1;
    d3 = -2.0f * (d1 * d1 + s * d2);
    return s;
}

// jet chain rule through tanh: a[] = pre-activation jet, nv[] = post-activation jet
__device__ __forceinline__ void jet_activate(const float* a, float* nv) {
    float d1, d2, d3;
    const float s = tanh_derivs(a[0], d1, d2, d3);
    const float gx = a[1], gy = a[2], gt = a[3];
    const float hxx = a[4], hxy = a[5], hyy = a[6];
    const float hxt = a[7], hyt = a[8];
    const float g2 = gx * gx + gy * gy;
    nv[0] = s;
    nv[1] = d1 * gx;  nv[2] = d1 * gy;  nv[3] = d1 * gt;
    nv[4] = fmaf(d2, gx * gx, d1 * hxx);
    nv[5] = fmaf(d2, gx * gy, d1 * hxy);
    nv[6] = fmaf(d2, gy * gy, d1 * hyy);
    nv[7] = fmaf(d2, gx * gt, d1 * hxt);
    nv[8] = fmaf(d2, gy * gt, d1 * hyt);
    nv[9]  = d3 * gx * g2 + d2 * (3.f * gx * hxx + 2.f * gy * hxy + gx * hyy) + d1 * a[9];
    nv[10] = d3 * gy * g2 + d2 * (3.f * gy * hyy + 2.f * gx * hxy + gy * hxx) + d1 * a[10];
}

// packed bf16 convert: dst.lo16 = bf16(a), dst.hi16 = bf16(b)  (RNE)
__device__ __forceinline__ u32 cvt_pk_bf16(float a, float b) {
    u32 r;
    asm("v_cvt_pk_bf16_f32 %0, %1, %2" : "=v"(r) : "v"(a), "v"(b));
    return r;
}

// hi word + exact residual lo word
__device__ __forceinline__ void pack_pair(float v0, float v1, u32& wh, u32& wl) {
    wh = cvt_pk_bf16(v0, v1);
    const float h0 = __uint_as_float(wh << 16);
    const float h1 = __uint_as_float(wh & 0xFFFF0000u);
    wl = cvt_pk_bf16(v0 - h0, v1 - h1);
}

__device__ __forceinline__ void input_neuron(int j, float xv, float yv, float tv,
                                             const float* __restrict__ W_in,
                                             const float* __restrict__ b_in, float* nv) {
    const float w0 = W_in[j], w1 = W_in[HID + j], w2 = W_in[2 * HID + j];
    const float a0 = fmaf(xv, w0, fmaf(yv, w1, fmaf(tv, w2, b_in[j])));
    float d1, d2, d3;
    const float s = tanh_derivs(a0, d1, d2, d3);
    const float g2w = w0 * w0 + w1 * w1;
    nv[0] = s;        nv[1] = d1 * w0;  nv[2] = d1 * w1;  nv[3] = d1 * w2;
    nv[4] = d2 * w0 * w0; nv[5] = d2 * w0 * w1; nv[6] = d2 * w1 * w1;
    nv[7] = d2 * w0 * w2; nv[8] = d2 * w1 * w2;
    nv[9] = d3 * w0 * g2w; nv[10] = d3 * w1 * g2w;
}

// ---- setup: pack W_hid (+bias at k=20) into MFMA A-fragments (hi/lo bf16) in ws ----
// HW-verified (r11/r13/r14): lane l holds m=l&15, e<4: k=4*(l>>4)+e ; e>=4: k=16+4*(l>>4)+(e-4)
__global__ void wfrag_setup(const float* __restrict__ W_hid,
                            const float* __restrict__ b_hid,
                            unsigned* __restrict__ wsu)
{
    const int l = threadIdx.x;
    const int g = l >> 4, m = l & 15;
    for (int layer = 0; layer < NLAY; ++layer) {
        for (int jt = 0; jt < 2; ++jt) {
            const int j = jt * 16 + m;
            unsigned hi[8], lo[8];
            for (int e = 0; e < 8; ++e) {
                const int k = (e < 4) ? (4 * g + e) : (16 + 4 * g + (e - 4));
                float w = 0.0f;
                if (j < HID) {
                    if (k < HID)       w = W_hid[(layer * HID + k) * HID + j];
                    else if (k == HID) w = b_hid[layer * HID + j];
                }
                const unsigned hb = __float_as_uint(w) & 0xFFFF0000u;
                const float lf = w - __uint_as_float(hb);
                hi[e] = hb >> 16;
                lo[e] = __float_as_uint(lf) >> 16;
            }
            unsigned* ph = wsu + (((layer * 2 + jt) * 2 + 0) * 64 + l) * 4;
            unsigned* pl = wsu + (((layer * 2 + jt) * 2 + 1) * 64 + l) * 4;
            for (int r = 0; r < 4; ++r) {
                ph[r] = hi[2 * r] | (hi[2 * r + 1] << 16);
                pl[r] = lo[2 * r] | (lo[2 * r + 1] << 16);
            }
        }
    }
}

__global__ void __launch_bounds__(256)
pinn_mfma_reg(const float* __restrict__ xs, const float* __restrict__ ys, const float* __restrict__ ts,
              const float* __restrict__ W_in, const float* __restrict__ b_in,
              const float* __restrict__ W_out, const float* __restrict__ b_out,
              const float* __restrict__ lam1p, const float* __restrict__ lam2p,
              const unsigned* __restrict__ wsu,
              float* __restrict__ out, int N)
{
    const int l  = threadIdx.x & 63;        // lane within wave
    const int wid = threadIdx.x >> 6;       // wave within block (0..3)
    const int g  = l >> 4, pt = l & 15;
    const int idx0 = blockIdx.x * (4 * PTS) + wid * PTS;
    const int pi = min(idx0 + pt, N - 1);

    // Layer-input B-fragments, register-resident.
    // comps 0..3 (val,gx,gy,gt): hi+lo (exact) — these feed the jet nonlinearly.
    // comps 4..10: hi-only bf16 — they propagate linearly (d1-contraction per layer)
    // and reach outputs with O(1) or lam2=0.01 weight; rounding fits the error budget.
    u32x4 Bh[NC], Bl[NLO];

    // ---- input layer ----
    const float xv = xs[pi], yv = ys[pi], tv = ts[pi];
    #pragma unroll
    for (int pr = 0; pr < 2; ++pr) {
        float nvA[NC], nvB[NC];
        input_neuron(4 * g + 2 * pr,     xv, yv, tv, W_in, b_in, nvA);
        input_neuron(4 * g + 2 * pr + 1, xv, yv, tv, W_in, b_in, nvB);
        #pragma unroll
        for (int c = 0; c < NC; ++c) {
            if (c < NLO) {
                u32 th, tl;
                pack_pair(nvA[c], nvB[c], th, tl);
                Bh[c][pr] = th; Bl[c][pr] = tl;
            } else {
                Bh[c][pr] = cvt_pk_bf16(nvA[c], nvB[c]);
            }
        }
    }
    if (g == 0) {
        #pragma unroll
        for (int pr = 0; pr < 2; ++pr) {
            float nvA[NC], nvB[NC];
            input_neuron(16 + 2 * pr,     xv, yv, tv, W_in, b_in, nvA);
            input_neuron(16 + 2 * pr + 1, xv, yv, tv, W_in, b_in, nvB);
            #pragma unroll
            for (int c = 0; c < NC; ++c) {
                if (c < NLO) {
                    u32 th, tl;
                    pack_pair(nvA[c], nvB[c], th, tl);
                    Bh[c][2 + pr] = th; Bl[c][2 + pr] = tl;
                } else {
                    Bh[c][2 + pr] = cvt_pk_bf16(nvA[c], nvB[c]);
                }
            }
        }
    } else {
        #pragma unroll
        for (int c = 0; c < NC; ++c) { Bh[c][2] = 0u; Bh[c][3] = 0u; }
        #pragma unroll
        for (int c = 0; c < NLO; ++c) { Bl[c][2] = 0u; Bl[c][3] = 0u; }
    }
    // bias row k=20 (g==1, e=4): X=1.0 in comp 0 only
    Bh[0][2] = (g == 1) ? 0x3F80u : Bh[0][2];
    Bl[0][2] = (g == 1) ? 0u      : Bl[0][2];

    // ---- hidden layers 0..NLAY-2: MFMA + activation + repack ----
    const u32x4* wp = (const u32x4*)wsu;
    u32x4 f0 = wp[0 * 64 + l];
    u32x4 f1 = wp[1 * 64 + l];
    u32x4 f2 = wp[2 * 64 + l];
    u32x4 f3 = wp[3 * 64 + l];

    #pragma unroll 1
    for (int layer = 0; layer < NLAY - 1; ++layer) {
        const int nl = layer + 1;
        u32x4 n0 = wp[(nl * 4 + 0) * 64 + l];
        u32x4 n1 = wp[(nl * 4 + 1) * 64 + l];
        u32x4 n2 = wp[(nl * 4 + 2) * 64 + l];
        u32x4 n3 = wp[(nl * 4 + 3) * 64 + l];

        const bf16x8 ah0 = __builtin_bit_cast(bf16x8, f0);
        const bf16x8 al0 = __builtin_bit_cast(bf16x8, f1);
        const bf16x8 ah1 = __builtin_bit_cast(bf16x8, f2);
        const bf16x8 al1 = __builtin_bit_cast(bf16x8, f3);

        f32x4 acc1[NC], acc2[NC];
        #pragma unroll
        for (int c = 0; c < NC; ++c) {
            const bf16x8 bh = __builtin_bit_cast(bf16x8, Bh[c]);
            const f32x4 z = (f32x4){0.f, 0.f, 0.f, 0.f};
            f32x4 a1 = __builtin_amdgcn_mfma_f32_16x16x32_bf16(ah0, bh, z, 0, 0, 0);
            f32x4 a2 = __builtin_amdgcn_mfma_f32_16x16x32_bf16(ah1, bh, z, 0, 0, 0);
            if (c < NLO) {
                const bf16x8 bl = __builtin_bit_cast(bf16x8, Bl[c]);
                a1 = __builtin_amdgcn_mfma_f32_16x16x32_bf16(ah0, bl, a1, 0, 0, 0);
                a2 = __builtin_amdgcn_mfma_f32_16x16x32_bf16(ah1, bl, a2, 0, 0, 0);
            }
            a1 = __builtin_amdgcn_mfma_f32_16x16x32_bf16(al0, bh, a1, 0, 0, 0);
            a2 = __builtin_amdgcn_mfma_f32_16x16x32_bf16(al1, bh, a2, 0, 0, 0);
            acc1[c] = a1;
            acc2[c] = a2;
        }

        // activation + repack (uniform across lanes: g>0 tile2 accs are exactly 0)
        #pragma unroll
        for (int pr = 0; pr < 2; ++pr) {
            float aA[NC], aB[NC], nvA[NC], nvB[NC];
            #pragma unroll
            for (int c = 0; c < NC; ++c) { aA[c] = acc1[c][2 * pr]; aB[c] = acc1[c][2 * pr + 1]; }
            jet_activate(aA, nvA);
            jet_activate(aB, nvB);
            #pragma unroll
            for (int c = 0; c < NC; ++c) {
                if (c < NLO) {
                    u32 th, tl;
                    pack_pair(nvA[c], nvB[c], th, tl);
                    Bh[c][pr] = th; Bl[c][pr] = tl;
                } else {
                    Bh[c][pr] = cvt_pk_bf16(nvA[c], nvB[c]);
                }
            }
        }
        #pragma unroll
        for (int pr = 0; pr < 2; ++pr) {
            float aA[NC], aB[NC], nvA[NC], nvB[NC];
            #pragma unroll
            for (int c = 0; c < NC; ++c) { aA[c] = acc2[c][2 * pr]; aB[c] = acc2[c][2 * pr + 1]; }
            jet_activate(aA, nvA);
            jet_activate(aB, nvB);
            #pragma unroll
            for (int c = 0; c < NC; ++c) {
                if (c < NLO) {
                    u32 th, tl;
                    pack_pair(nvA[c], nvB[c], th, tl);
                    Bh[c][2 + pr] = th; Bl[c][2 + pr] = tl;
                } else {
                    Bh[c][2 + pr] = cvt_pk_bf16(nvA[c], nvB[c]);
                }
            }
        }
        Bh[0][2] = (g == 1) ? 0x3F80u : Bh[0][2];
        Bl[0][2] = (g == 1) ? 0u      : Bl[0][2];

        f0 = n0; f1 = n1; f2 = n2; f3 = n3;
    }

    // ---- last hidden layer: MFMA + activation fused directly into output reduction ----
    float su = 0, sv = 0, sp = 0, spx = 0, spy = 0, svx = 0;
    float sux = 0, suy = 0, svt = 0, sut = 0, slx = 0, sly = 0;
    {
        const bf16x8 ah0 = __builtin_bit_cast(bf16x8, f0);
        const bf16x8 al0 = __builtin_bit_cast(bf16x8, f1);
        const bf16x8 ah1 = __builtin_bit_cast(bf16x8, f2);
        const bf16x8 al1 = __builtin_bit_cast(bf16x8, f3);

        f32x4 acc1[NC], acc2[NC];
        #pragma unroll
        for (int c = 0; c < NC; ++c) {
            const bf16x8 bh = __builtin_bit_cast(bf16x8, Bh[c]);
            const f32x4 z = (f32x4){0.f, 0.f, 0.f, 0.f};
            f32x4 a1 = __builtin_amdgcn_mfma_f32_16x16x32_bf16(ah0, bh, z, 0, 0, 0);
            f32x4 a2 = __builtin_amdgcn_mfma_f32_16x16x32_bf16(ah1, bh, z, 0, 0, 0);
            if (c < NLO) {
                const bf16x8 bl = __builtin_bit_cast(bf16x8, Bl[c]);
                a1 = __builtin_amdgcn_mfma_f32_16x16x32_bf16(ah0, bl, a1, 0, 0, 0);
                a2 = __builtin_amdgcn_mfma_f32_16x16x32_bf16(ah1, bl, a2, 0, 0, 0);
            }
            a1 = __builtin_amdgcn_mfma_f32_16x16x32_bf16(al0, bh, a1, 0, 0, 0);
            a2 = __builtin_amdgcn_mfma_f32_16x16x32_bf16(al1, bh, a2, 0, 0, 0);
            acc1[c] = a1;
            acc2[c] = a2;
        }

        // tile1 slots: j = 4g+s, all real
        #pragma unroll
        for (int s = 0; s < 4; ++s) {
            float a[NC], nv[NC];
            #pragma unroll
            for (int c = 0; c < NC; ++c) a[c] = acc1[c][s];
            jet_activate(a, nv);
            const int j = 4 * g + s;
            const float w0 = W_out[2 * j], w1 = W_out[2 * j + 1];
            sp  = fmaf(w1, nv[0], sp);
            sv  = fmaf(w0, nv[1], sv);    spx = fmaf(w1, nv[1], spx);
            su  = fmaf(w0, nv[2], su);    spy = fmaf(w1, nv[2], spy);
            svx = fmaf(w0, nv[4], svx);
            sux = fmaf(w0, nv[5], sux);
            suy = fmaf(w0, nv[6], suy);
            svt = fmaf(w0, nv[7], svt);
            sut = fmaf(w0, nv[8], sut);
            slx = fmaf(w0, nv[9], slx);
            sly = fmaf(w0, nv[10], sly);
        }
        // tile2 slots: j2 = 16+4g+s, real only for j2 < 20 (g==0); others zero accs + masked w
        #pragma unroll
        for (int s = 0; s < 4; ++s) {
            float a[NC], nv[NC];
            #pragma unroll
            for (int c = 0; c < NC; ++c) a[c] = acc2[c][s];
            jet_activate(a, nv);
            const int j2 = 16 + 4 * g + s;
            const int jc = (j2 < HID) ? j2 : 0;
            const float valid = (j2 < HID) ? 1.0f : 0.0f;
            const float w0 = W_out[2 * jc] * valid, w1 = W_out[2 * jc + 1] * valid;
            sp  = fmaf(w1, nv[0], sp);
            sv  = fmaf(w0, nv[1], sv);    spx = fmaf(w1, nv[1], spx);
            su  = fmaf(w0, nv[2], su);    spy = fmaf(w1, nv[2], spy);
            svx = fmaf(w0, nv[4], svx);
            sux = fmaf(w0, nv[5], sux);
            suy = fmaf(w0, nv[6], suy);
            svt = fmaf(w0, nv[7], svt);
            sut = fmaf(w0, nv[8], sut);
            slx = fmaf(w0, nv[9], slx);
            sly = fmaf(w0, nv[10], sly);
        }
    }

    // reduce over the 4 lane-groups (lanes l, l^16, l^32, l^48 share pt)
    #define RED_(x) x += __shfl_xor(x, 16); x += __shfl_xor(x, 32)
    RED_(su); RED_(sv); RED_(sp); RED_(spx); RED_(spy); RED_(svx);
    RED_(sux); RED_(suy); RED_(svt); RED_(sut); RED_(slx); RED_(sly);
    #undef RED_

    if (g == 0 && idx0 + pt < N) {
        const float l1 = lam1p[0], l2 = lam2p[0];
        const float u = su, v = -sv, p = sp + b_out[1];
        const float fu = sut + l1 * (u * sux + v * suy) + spx - l2 * sly;
        const float fv = -svt + l1 * (u * (-svx) + v * (-sux)) + spy + l2 * slx;
        out[idx0 + pt]         = u;
        out[N + idx0 + pt]     = v;
        out[2 * N + idx0 + pt] = p;
        out[3 * N + idx0 + pt] = fu;
        out[4 * N + idx0 + pt] = fv;
    }
}

extern "C" void kernel_launch(void* const* d_in, const int* in_sizes, int n_in,
                              void* d_out, int out_size, void* d_ws, size_t ws_size,
                              hipStream_t stream) {
    const float* xs    = (const float*)d_in[0];
    const float* ys    = (const float*)d_in[1];
    const float* ts    = (const float*)d_in[2];
    const float* W_in  = (const float*)d_in[3];
    const float* b_in  = (const float*)d_in[4];
    const float* W_hid = (const float*)d_in[5];
    const float* b_hid = (const float*)d_in[6];
    const float* W_out = (const float*)d_in[7];
    const float* b_out = (const float*)d_in[8];
    const float* lam1  = (const float*)d_in[9];
    const float* lam2  = (const float*)d_in[10];
    float* out = (float*)d_out;

    const int N = in_sizes[0];
    wfrag_setup<<<1, 64, 0, stream>>>(W_hid, b_hid, (unsigned*)d_ws);
    const int grid = (N + 4 * PTS - 1) / (4 * PTS);
    pinn_mfma_reg<<<grid, 256, 0, stream>>>(xs, ys, ts, W_in, b_in, W_out, b_out,
                                            lam1, lam2, (const unsigned*)d_ws, out, N);
}